// Round 5
// baseline (619.435 us; speedup 1.0000x reference)
//
#include <hip/hip_runtime.h>
#include <hip/hip_bf16.h>

#define DIMN 2048
#define NQKV 6144
#define NH 16
#define HD 128
#define BSZ 2
#define SEQ 2048
#define ROWS (BSZ*SEQ)   // 4096

typedef short short8 __attribute__((ext_vector_type(8)));
typedef float f32x4 __attribute__((ext_vector_type(4)));

__device__ __forceinline__ unsigned short f2bf(float f) {
    __hip_bfloat16 h = __float2bfloat16(f);
    unsigned short u; __builtin_memcpy(&u, &h, 2); return u;
}

__device__ __forceinline__ void gld_lds16(const void* g, void* l) {
    __builtin_amdgcn_global_load_lds(
        (const __attribute__((address_space(1))) void*)g,
        (__attribute__((address_space(3))) void*)l, 16, 0, 0);
}

// ---------------- fused f32 -> bf16 converts ----------------
__global__ void cvt_all(const float* __restrict__ x, const float* __restrict__ wq,
                        const float* __restrict__ wk, const float* __restrict__ wv,
                        const float* __restrict__ wo,
                        unsigned short* __restrict__ Xb, unsigned short* __restrict__ Wcat,
                        unsigned short* __restrict__ Wo2) {
    int bid = blockIdx.x;
    const float* in; unsigned short* out; int base;
    if      (bid <  8192) { in = x;  out = Xb;             base = bid; }
    else if (bid < 12288) { in = wq; out = Wcat;           base = bid - 8192; }
    else if (bid < 16384) { in = wk; out = Wcat + 4194304; base = bid - 12288; }
    else if (bid < 20480) { in = wv; out = Wcat + 8388608; base = bid - 16384; }
    else                  { in = wo; out = Wo2;            base = bid - 20480; }
    int i = (base * 256 + threadIdx.x) * 4;
    float4 v = *(const float4*)(in + i);
    ushort4 o; o.x = f2bf(v.x); o.y = f2bf(v.y); o.z = f2bf(v.z); o.w = f2bf(v.w);
    *(ushort4*)(out + i) = o;
}

// ================= window-pipelined GEMM: C[m][n] = sum_k A[m][k]*B[n][k] =================
// MODE 0 (QKV): BM=256 BN=384, 768 thr (12 waves 2Mx6N), per-wave 128x64 (MR=8,NR=4),
//               LDS 160 KB, grid 256 = 1 exact round.  bf16 out + QKV bias + fused RoPE.
// MODE 1 (out): BM=128 BN=256, 512 thr (8 waves 2Mx4N), per-wave 64x64 (MR=4,NR=4),
//               LDS 96 KB, grid 256 = 1 round.  f32 out + bias, B(=W2) selected per batch.
// Per K-tile window, 4 phases:
//   p1: ds_read A(qm0)+B(qn0) [12/8 reads] + stage A(kt+1);  bar; lgkm0; MFMA(0,0)
//   p2: ds_read B(qn1)                     + stage B(kt+1);  bar; lgkm0; MFMA(0,1)
//   p3: ds_read A(qm1);                                      bar; lgkm0; MFMA(1,0)
//   p4: MFMA(1,1); vmcnt(0); bar          (vmcnt's loads were issued 2.5-3 phases ago)
// Buffer safety: stage(kt+1)->buf b̄ issues only after b̄'s last reads (prev window p2/p3)
// were lgkm-retired before the prev window-end barrier; window-end vmcnt+bar collectivizes
// data-ready across waves (waves 8-11 of MODE0 don't issue A loads).
// Swizzle: 16B-col' = col ^ (row&7); source pre-swizzled so gld_lds dest stays linear.

template<int MODE>
__global__ __launch_bounds__(MODE==0?768:512) void gemm_w4(
    const unsigned short* __restrict__ A, int lda,
    const unsigned short* __restrict__ B, int ldb,
    const float* __restrict__ b0, const float* __restrict__ b1, const float* __restrict__ b2,
    const float* __restrict__ fcos, const float* __restrict__ fsin,
    void* __restrict__ C, int ldc, int K)
{
    constexpr int TH   = MODE==0 ? 768 : 512;
    constexpr int BM   = MODE==0 ? 256 : 128;
    constexpr int BN   = MODE==0 ? 384 : 256;
    constexpr int WN   = MODE==0 ? 6 : 4;
    constexpr int MR   = MODE==0 ? 8 : 4;
    constexpr int NR   = 4;
    constexpr int AH   = BM/2, BH = BN/2;
    constexpr int AHE  = AH*64, BHE = BH*64;
    constexpr int ABUF = 2*AHE, BBUF = 2*BHE;
    constexpr int AISS = BM/64;      // A stage issues (by first 512 threads)
    constexpr int BRS  = BN/4;       // B row stride per stage issue
    constexpr int NT   = MODE==0 ? 16 : 8;   // n-tiles

    __shared__ __align__(16) unsigned short As[2*ABUF];  // MODE0: 64 KB, MODE1: 32 KB
    __shared__ __align__(16) unsigned short Bs[2*BBUF];  // MODE0: 96 KB, MODE1: 64 KB

    const int t  = threadIdx.x;
    const int l  = t & 63;
    const int w  = t >> 6;
    const int wr = w / WN;
    const int wc = w % WN;
    const int fr = l & 15, fq = l >> 4;

    // XCD-aware swizzle over 256 blocks (1-D grid)
    const int lin = blockIdx.x;
    const int u   = (lin & 7) * 32 + (lin >> 3);
    const int n0  = (u % NT) * BN;
    const int m0  = (u / NT) * BM;

    const unsigned short* Bsel = B;
    if (MODE == 1 && m0 >= 2048) Bsel += (size_t)2048 * 2048;  // per-batch W2

    // staging sources (pre-swizzled col; gld_lds dest linear)
    const int srow = t >> 3;
    const int scol = ((t & 7) ^ (srow & 7)) * 8;
    const unsigned short* aS = A    + (size_t)(m0 + srow) * lda + scol;
    const unsigned short* bS = Bsel + (size_t)(n0 + srow) * ldb + scol;

#define STAGE_A(KT) do { if (MODE == 1 || w < 8) { \
    const unsigned short* s_ = aS + (size_t)(KT) * 64; \
    unsigned short* d_ = &As[((KT) & 1) * ABUF + t * 8]; \
    _Pragma("unroll") for (int j = 0; j < AISS; ++j) \
      gld_lds16(s_ + (size_t)j * 64 * lda, d_ + j * 4096); \
  } } while (0)

#define STAGE_B(KT) do { \
    const unsigned short* s_ = bS + (size_t)(KT) * 64; \
    unsigned short* d_ = &Bs[((KT) & 1) * BBUF + t * 8]; \
    _Pragma("unroll") for (int j = 0; j < 4; ++j) \
      gld_lds16(s_ + (size_t)j * BRS * ldb, d_ + j * (TH * 8)); \
  } while (0)

    // fragment read bases (swizzled): row&7 == fr&7 everywhere (all row offsets %8==0)
    const int swz = fr & 7;
    const int c0 = (fq ^ swz) * 8;          // kk=0
    const int c1 = ((4 + fq) ^ swz) * 8;    // kk=1
    const int bh    = (wc * 64) / BH;
    const int aRowB = wr * AHE + fr * 64;
    const int bRowB = bh * BHE + (wc * 64 - bh * BH + fr) * 64;

    short8 aF[MR/2][2], bF[2][NR/2][2];
    f32x4  acc[MR][NR] = {};

#define RD_A(DD, QM) do { _Pragma("unroll") for (int m2 = 0; m2 < MR/2; ++m2) { \
    aF[m2][0] = *(const short8*)&As[(DD) + aRowB + ((QM)*(MR/2)+m2)*1024 + c0]; \
    aF[m2][1] = *(const short8*)&As[(DD) + aRowB + ((QM)*(MR/2)+m2)*1024 + c1]; } } while (0)

#define RD_B(DD, QN) do { _Pragma("unroll") for (int n2 = 0; n2 < NR/2; ++n2) { \
    bF[QN][n2][0] = *(const short8*)&Bs[(DD) + bRowB + ((QN)*(NR/2)+n2)*1024 + c0]; \
    bF[QN][n2][1] = *(const short8*)&Bs[(DD) + bRowB + ((QN)*(NR/2)+n2)*1024 + c1]; } } while (0)

#define PH_MFMA(QM, QN) do { \
    asm volatile("s_waitcnt lgkmcnt(0)"); \
    __builtin_amdgcn_sched_barrier(0); \
    __builtin_amdgcn_s_setprio(1); \
    _Pragma("unroll") for (int m2 = 0; m2 < MR/2; ++m2) \
      _Pragma("unroll") for (int n2 = 0; n2 < NR/2; ++n2) \
        _Pragma("unroll") for (int kk = 0; kk < 2; ++kk) \
          acc[(QM)*(MR/2)+m2][(QN)*(NR/2)+n2] = __builtin_amdgcn_mfma_f32_16x16x32_bf16( \
              aF[m2][kk], bF[QN][n2][kk], acc[(QM)*(MR/2)+m2][(QN)*(NR/2)+n2], 0, 0, 0); \
    __builtin_amdgcn_s_setprio(0); \
    __builtin_amdgcn_sched_barrier(0); \
  } while (0)

    const int ktT = K >> 6;   // 32

    // prologue: stage K-tile 0 into buf0
    STAGE_A(0); STAGE_B(0);
    asm volatile("s_waitcnt vmcnt(0)");
    __builtin_amdgcn_sched_barrier(0);
    __builtin_amdgcn_s_barrier();

    #pragma unroll 2
    for (int kt = 0; kt < ktT; ++kt) {
        const int DA = (kt & 1) * ABUF, DB = (kt & 1) * BBUF;
        const bool stg = (kt + 1 < ktT);
        // p1
        RD_A(DA, 0); RD_B(DB, 0);
        if (stg) STAGE_A(kt + 1);
        __builtin_amdgcn_s_barrier();
        PH_MFMA(0, 0);
        // p2
        RD_B(DB, 1);
        if (stg) STAGE_B(kt + 1);
        __builtin_amdgcn_s_barrier();
        PH_MFMA(0, 1);
        // p3
        RD_A(DA, 1);
        __builtin_amdgcn_s_barrier();
        PH_MFMA(1, 0);
        // p4
        PH_MFMA(1, 1);
        asm volatile("s_waitcnt vmcnt(0)");
        __builtin_amdgcn_sched_barrier(0);
        __builtin_amdgcn_s_barrier();
    }

#undef PH_MFMA
#undef RD_A
#undef RD_B
#undef STAGE_A
#undef STAGE_B

    // ---- epilogue: bias (+ RoPE for MODE 0 on cols < 4096), store
    #pragma unroll
    for (int mi = 0; mi < MR; ++mi) {
        #pragma unroll
        for (int ni = 0; ni < NR; ++ni) {
            #pragma unroll
            for (int j = 0; j < 4; ++j) {
                const int r  = m0 + wr * (BM/2) + mi * 16 + fq * 4 + j;
                const int cg = n0 + wc * 64 + ni * 16 + fr;
                float v = acc[mi][ni][j];
                if (MODE == 0) {
                    v += (cg < 2048) ? b0[cg] : ((cg < 4096) ? b1[cg - 2048] : b2[cg - 4096]);
                    if (cg < 4096) {  // block-uniform: RoPE on Q and K
                        const int s = r & (SEQ - 1);
                        const int i = (cg >> 1) & 63;
                        const float cs = fcos[s * 64 + i];
                        const float sn = fsin[s * 64 + i];
                        const float p  = __shfl_xor(v, 1);
                        v = (fr & 1) ? (p * sn + v * cs) : (v * cs - p * sn);
                    }
                    ((unsigned short*)C)[(size_t)r * ldc + cg] = f2bf(v);
                } else {
                    v += b0[cg];
                    ((float*)C)[(size_t)r * ldc + cg] = v;
                }
            }
        }
    }
}

// ---------------- 128x128 GEMM core (small GEMMs) ----------------
template<int OUT_BF16, int HAS_BIAS>
__device__ __forceinline__ void gemm_tile_core(
    const unsigned short* __restrict__ A, int lda,
    const unsigned short* __restrict__ B, int ldb,
    const float* __restrict__ bias,
    void* __restrict__ Cptr, int ldc, int K)
{
    __shared__ __align__(16) unsigned short As[128 * 64];
    __shared__ __align__(16) unsigned short Bs[128 * 64];

    const int t  = threadIdx.x;
    const int l  = t & 63;
    const int w  = t >> 6;
    const int wr = w >> 1, wc = w & 1;
    const int fr = l & 15, fq = l >> 4;

    f32x4 acc[4][4] = {};

    const int srow = t >> 3;
    const int scol = (t & 7) * 8;

    for (int k0 = 0; k0 < K; k0 += 64) {
        __syncthreads();
        #pragma unroll
        for (int r = 0; r < 4; ++r) {
            gld_lds16(A + (size_t)(r * 32 + srow) * lda + k0 + scol, &As[(r * 32 + srow) * 64 + scol]);
            gld_lds16(B + (size_t)(r * 32 + srow) * ldb + k0 + scol, &Bs[(r * 32 + srow) * 64 + scol]);
        }
        __syncthreads();
        #pragma unroll
        for (int kk = 0; kk < 2; ++kk) {
            short8 a[4], b[4];
            #pragma unroll
            for (int mi = 0; mi < 4; ++mi)
                a[mi] = *(const short8*)&As[(wr * 64 + mi * 16 + fr) * 64 + kk * 32 + fq * 8];
            #pragma unroll
            for (int ni = 0; ni < 4; ++ni)
                b[ni] = *(const short8*)&Bs[(wc * 64 + ni * 16 + fr) * 64 + kk * 32 + fq * 8];
            #pragma unroll
            for (int mi = 0; mi < 4; ++mi)
                #pragma unroll
                for (int ni = 0; ni < 4; ++ni)
                    acc[mi][ni] = __builtin_amdgcn_mfma_f32_16x16x32_bf16(a[mi], b[ni], acc[mi][ni], 0, 0, 0);
        }
    }

    #pragma unroll
    for (int mi = 0; mi < 4; ++mi) {
        #pragma unroll
        for (int ni = 0; ni < 4; ++ni) {
            #pragma unroll
            for (int j = 0; j < 4; ++j) {
                int rr = wr * 64 + mi * 16 + fq * 4 + j;
                int cc = wc * 64 + ni * 16 + fr;
                float v = acc[mi][ni][j];
                if (HAS_BIAS) v += bias[cc];
                if (OUT_BF16) ((unsigned short*)Cptr)[(size_t)rr * ldc + cc] = f2bf(v);
                else          ((float*)Cptr)[(size_t)rr * ldc + cc] = v;
            }
        }
    }
}

// ---------------- K^T/V partials: part[bh][ks][d1][d2] = sum_s K[s][d1]*V[s][d2] ----------------
__global__ __launch_bounds__(256) void ktv_kernel(
    const unsigned short* __restrict__ QKV, float* __restrict__ part)
{
    const int ks = blockIdx.x;  // 0..7
    const int bh = blockIdx.y;  // 0..31
    const int b = bh >> 4, h = bh & 15;
    const unsigned short* Kbase = QKV + (size_t)(b * SEQ + ks * 256) * NQKV + 2048 + h * HD;
    const unsigned short* Vbase = QKV + (size_t)(b * SEQ + ks * 256) * NQKV + 4096 + h * HD;

    __shared__ __align__(16) unsigned short Ks_[64 * 128];
    __shared__ __align__(16) unsigned short Vs_[64 * 128];

    const int t  = threadIdx.x;
    const int l  = t & 63;
    const int w  = t >> 6;
    const int wr = w >> 1, wc = w & 1;
    const int fr = l & 15, fq = l >> 4;

    f32x4 acc[4][4] = {};

    const int srow = t >> 4;
    const int scol = (t & 15) * 8;

    for (int sc = 0; sc < 4; ++sc) {
        __syncthreads();
        #pragma unroll
        for (int r = 0; r < 4; ++r) {
            gld_lds16(Kbase + (size_t)(sc * 64 + r * 16 + srow) * NQKV + scol, &Ks_[(r * 16 + srow) * 128 + scol]);
            gld_lds16(Vbase + (size_t)(sc * 64 + r * 16 + srow) * NQKV + scol, &Vs_[(r * 16 + srow) * 128 + scol]);
        }
        __syncthreads();
        #pragma unroll
        for (int kk = 0; kk < 2; ++kk) {
            short8 a[4], bb[4];
            #pragma unroll
            for (int mi = 0; mi < 4; ++mi)
                #pragma unroll
                for (int i = 0; i < 8; ++i)
                    a[mi][i] = (short)Ks_[(kk * 32 + fq * 8 + i) * 128 + wr * 64 + mi * 16 + fr];
            #pragma unroll
            for (int ni = 0; ni < 4; ++ni)
                #pragma unroll
                for (int i = 0; i < 8; ++i)
                    bb[ni][i] = (short)Vs_[(kk * 32 + fq * 8 + i) * 128 + wc * 64 + ni * 16 + fr];
            #pragma unroll
            for (int mi = 0; mi < 4; ++mi)
                #pragma unroll
                for (int ni = 0; ni < 4; ++ni)
                    acc[mi][ni] = __builtin_amdgcn_mfma_f32_16x16x32_bf16(a[mi], bb[ni], acc[mi][ni], 0, 0, 0);
        }
    }

    float* base = part + ((size_t)bh * 8 + ks) * 16384;
    #pragma unroll
    for (int mi = 0; mi < 4; ++mi)
        #pragma unroll
        for (int ni = 0; ni < 4; ++ni)
            #pragma unroll
            for (int j = 0; j < 4; ++j)
                base[(wr * 64 + mi * 16 + fq * 4 + j) * 128 + wc * 64 + ni * 16 + fr] = acc[mi][ni][j];
}

// ---------------- reduce partials, scale, -> bf16 M2t[bh][d1][d2] ----------------
__global__ void ktv_reduce(const float* __restrict__ part, unsigned short* __restrict__ M2t) {
    int idx = blockIdx.x * 256 + threadIdx.x;
    int bh = idx >> 14, rem = idx & 16383;
    const float* p = part + ((size_t)bh * 8) * 16384 + rem;
    float s = 0.f;
    #pragma unroll
    for (int k = 0; k < 8; ++k) s += p[(size_t)k * 16384];
    M2t[idx] = f2bf(s * 0.08838834764831845f);  // 1/sqrt(128)
}

// ---------------- W2[b][i][h*128+d1] = sum_d2 Wo[i][h*128+d2] * M2t[bh][d1][d2] ----------------
__global__ __launch_bounds__(256) void w2_gemm(
    const unsigned short* __restrict__ Wo2, const unsigned short* __restrict__ M2t,
    unsigned short* __restrict__ W2)
{
    const int mt = blockIdx.x;   // 0..15
    const int bh = blockIdx.y;   // 0..31
    const int b = bh >> 4, h = bh & 15;
    const unsigned short* A = Wo2 + (size_t)(mt * 128) * DIMN + h * HD;
    const unsigned short* B = M2t + (size_t)bh * HD * HD;
    unsigned short* Cp = W2 + (size_t)b * DIMN * DIMN + (size_t)(mt * 128) * DIMN + h * HD;
    gemm_tile_core<1, 0>(A, DIMN, B, HD, nullptr, Cp, DIMN, HD);
}

extern "C" void kernel_launch(void* const* d_in, const int* in_sizes, int n_in,
                              void* d_out, int out_size, void* d_ws, size_t ws_size,
                              hipStream_t stream) {
    const float* x    = (const float*)d_in[0];
    const float* fcos = (const float*)d_in[1];
    const float* fsin = (const float*)d_in[2];
    const float* wq   = (const float*)d_in[3];
    const float* bq   = (const float*)d_in[4];
    const float* wk   = (const float*)d_in[5];
    const float* bk   = (const float*)d_in[6];
    const float* wv   = (const float*)d_in[7];
    const float* bv   = (const float*)d_in[8];
    const float* wo   = (const float*)d_in[9];
    const float* bo   = (const float*)d_in[10];
    float* out = (float*)d_out;

    char* ws = (char*)d_ws;
    size_t off = 0;
    auto alloc = [&](size_t bytes) { char* p = ws + off; off += (bytes + 255) & ~(size_t)255; return p; };

    unsigned short* Xb   = (unsigned short*)alloc((size_t)ROWS * DIMN * 2);
    unsigned short* Wcat = (unsigned short*)alloc((size_t)NQKV * DIMN * 2);
    unsigned short* Wo2  = (unsigned short*)alloc((size_t)DIMN * DIMN * 2);
    unsigned short* QKV  = (unsigned short*)alloc((size_t)ROWS * NQKV * 2);
    float*          part = (float*)alloc((size_t)32 * 8 * HD * HD * 4);
    unsigned short* M2t  = (unsigned short*)alloc((size_t)32 * HD * HD * 2);
    unsigned short* W2   = (unsigned short*)alloc((size_t)BSZ * DIMN * DIMN * 2);

    // all converts in one launch
    cvt_all<<<24576, 256, 0, stream>>>(x, wq, wk, wv, wo, Xb, Wcat, Wo2);

    // fused QKV projection + bias + RoPE  (M=4096, N=6144, K=2048): 256 blocks = 1 round
    gemm_w4<0><<<256, 768, 0, stream>>>(
        Xb, DIMN, Wcat, DIMN, bq, bk, bv, fcos, fsin, QKV, NQKV, DIMN);

    // reassociated attention (no softmax): M2t = (K^T V)^T/sqrt(d) per (b,h)
    ktv_kernel<<<dim3(8, 32), 256, 0, stream>>>(QKV, part);
    ktv_reduce<<<(32 * 16384) / 256, 256, 0, stream>>>(part, M2t);

    // fold attention + output projection: W2_b = concat_h(Wo_h @ M2_{b,h})
    w2_gemm<<<dim3(16, 32), 256, 0, stream>>>(Wo2, M2t, W2);

    // out = Q @ W2_b^T + bo  (M=4096, N=2048, K=2048): 256 blocks = 1 round
    gemm_w4<1><<<256, 512, 0, stream>>>(
        QKV, NQKV, W2, DIMN, bo, nullptr, nullptr, nullptr, nullptr, out, DIMN, DIMN);
}

// Round 6
// 246.982 us; speedup vs baseline: 2.5080x; 2.5080x over previous
//
#include <hip/hip_runtime.h>
#include <hip/hip_bf16.h>

#define DIMN 2048
#define NQKV 6144
#define NH 16
#define HD 128
#define BSZ 2
#define SEQ 2048
#define ROWS (BSZ*SEQ)   // 4096

typedef short short8 __attribute__((ext_vector_type(8)));
typedef float f32x4 __attribute__((ext_vector_type(4)));

__device__ __forceinline__ unsigned short f2bf(float f) {
    __hip_bfloat16 h = __float2bfloat16(f);
    unsigned short u; __builtin_memcpy(&u, &h, 2); return u;
}

__device__ __forceinline__ void gld_lds16(const void* g, void* l) {
    __builtin_amdgcn_global_load_lds(
        (const __attribute__((address_space(1))) void*)g,
        (__attribute__((address_space(3))) void*)l, 16, 0, 0);
}

// ---------------- fused f32 -> bf16 converts ----------------
__global__ void cvt_all(const float* __restrict__ x, const float* __restrict__ wq,
                        const float* __restrict__ wk, const float* __restrict__ wv,
                        const float* __restrict__ wo,
                        unsigned short* __restrict__ Xb, unsigned short* __restrict__ Wcat,
                        unsigned short* __restrict__ Wo2) {
    int bid = blockIdx.x;
    const float* in; unsigned short* out; int base;
    if      (bid <  8192) { in = x;  out = Xb;             base = bid; }
    else if (bid < 12288) { in = wq; out = Wcat;           base = bid - 8192; }
    else if (bid < 16384) { in = wk; out = Wcat + 4194304; base = bid - 12288; }
    else if (bid < 20480) { in = wv; out = Wcat + 8388608; base = bid - 16384; }
    else                  { in = wo; out = Wo2;            base = bid - 20480; }
    int i = (base * 256 + threadIdx.x) * 4;
    float4 v = *(const float4*)(in + i);
    ushort4 o; o.x = f2bf(v.x); o.y = f2bf(v.y); o.z = f2bf(v.z); o.w = f2bf(v.w);
    *(ushort4*)(out + i) = o;
}

// ================= m201-style 256x256 8-phase GEMM: C[m][n] = sum_k A[m][k]*B[n][k] ===========
// BK=64, 512 threads, 8 waves (2M x 4N), per-wave 128x64 (acc[8][4] = 128 VGPR; 2 waves/SIMD
// at <=256 VGPR cap -> NO spill, the r5 failure mode). LDS 128 KB: A,B each [2buf][2half][128][64].
// Per tile T (4 phases, 2 barriers each):
//  P1: RD A(qm0) 8 + B(qn0) 4 reads; stage A0(T+1); lgkm(8); bar; lgkm(0); MFMA(qm0,qn0); bar
//  P2: RD B(qn1) 4;                  stage A1(T+1);          bar; lgkm(0); MFMA(qm0,qn1); bar
//  P3: RD A(qm1) 8;                  stage B0(T+2);          bar; lgkm(0); MFMA(qm1,qn0); bar
//  P4:                               stage B1(T+2); MFMA(qm1,qn1); vmcnt(4); bar
// Safety: each stage's target-LDS last reader retired at a lgkmcnt(0) preceding an earlier
// barrier (A(T+1) buf free after T-1 P3-bar; B(T+2) buf free after T P2-bar).
// vmcnt(4) retires all 8 loads of tile T+1, leaves B(T+2)'s 4 in flight. Tail: vmcnt(0).
// Swizzle: 16B-col' = col ^ (row&7); source pre-swizzled so gld_lds dest stays linear.
// MODE 0: bf16 out + QKV region bias + fused RoPE.  MODE 1: f32 out + bias, B per batch.

template<int MODE>
__global__ __launch_bounds__(512, 2) void gemm256(
    const unsigned short* __restrict__ A, int lda,
    const unsigned short* __restrict__ B, int ldb,
    const float* __restrict__ b0, const float* __restrict__ b1, const float* __restrict__ b2,
    const float* __restrict__ fcos, const float* __restrict__ fsin,
    void* __restrict__ C, int ldc, int K)
{
    __shared__ __align__(16) unsigned short As[32768];  // 64 KB: [2][2][128][64]
    __shared__ __align__(16) unsigned short Bs[32768];  // 64 KB

    const int t  = threadIdx.x;
    const int l  = t & 63;
    const int w  = t >> 6;
    const int wr = w >> 2;          // 0..1
    const int wc = w & 3;           // 0..3
    const int fr = l & 15, fq = l >> 4;

    constexpr int NT  = MODE == 0 ? 24 : 8;
    constexpr int CPX = MODE == 0 ? 48 : 16;   // blocks per XCD
    const int lin = blockIdx.x;
    const int u   = (lin & 7) * CPX + (lin >> 3);
    const int n0  = (u % NT) * 256;
    const int m0  = (u / NT) * 256;

    const unsigned short* Bsel = B;
    if (MODE == 1 && m0 >= 2048) Bsel += (size_t)2048 * 2048;  // per-batch W2

    // staging sources (pre-swizzled col; gld_lds dest linear)
    const int srow = t >> 3;                        // 0..63
    const int scol = ((t & 7) ^ (srow & 7)) * 8;
    const unsigned short* aS = A    + (size_t)(m0 + srow) * lda + scol;
    const unsigned short* bS = Bsel + (size_t)(n0 + srow) * ldb + scol;

#define STG_A(KT, H) do { \
    const unsigned short* s_ = aS + (size_t)(H) * 128 * lda + (size_t)(KT) * 64; \
    gld_lds16(s_,                    &As[(((KT) & 1) << 14) + ((H) << 13) + t * 8]); \
    gld_lds16(s_ + (size_t)64 * lda, &As[(((KT) & 1) << 14) + ((H) << 13) + 4096 + t * 8]); \
  } while (0)
#define STG_B(KT, H) do { \
    const unsigned short* s_ = bS + (size_t)(H) * 128 * ldb + (size_t)(KT) * 64; \
    gld_lds16(s_,                    &Bs[(((KT) & 1) << 14) + ((H) << 13) + t * 8]); \
    gld_lds16(s_ + (size_t)64 * ldb, &Bs[(((KT) & 1) << 14) + ((H) << 13) + 4096 + t * 8]); \
  } while (0)

    // reader offsets (swizzled; all row offsets %8==0 so key = fr&7)
    const int cK0 = (fq ^ (fr & 7)) * 8;
    const int cK1 = ((4 + fq) ^ (fr & 7)) * 8;
    const int aB0 = wr * 8192 + fr * 64;   // + qm*4096 + m2*1024
    const int bB0 = wc * 4096 + fr * 64;   // + qn*2048 + n2*1024

    short8 aF[4][2], bF0[2][2], bF1[2][2];
    f32x4  acc[8][4] = {};

#define RD_A(DD, QM) do { _Pragma("unroll") for (int m2 = 0; m2 < 4; ++m2) { \
    aF[m2][0] = *(const short8*)&As[(DD) + aB0 + (QM) * 4096 + m2 * 1024 + cK0]; \
    aF[m2][1] = *(const short8*)&As[(DD) + aB0 + (QM) * 4096 + m2 * 1024 + cK1]; } } while (0)
#define RD_B(DD, QN, BF) do { _Pragma("unroll") for (int n2 = 0; n2 < 2; ++n2) { \
    BF[n2][0] = *(const short8*)&Bs[(DD) + bB0 + (QN) * 2048 + n2 * 1024 + cK0]; \
    BF[n2][1] = *(const short8*)&Bs[(DD) + bB0 + (QN) * 2048 + n2 * 1024 + cK1]; } } while (0)

#define MM(QM, QN, BF) do { \
    asm volatile("s_waitcnt lgkmcnt(0)"); \
    __builtin_amdgcn_sched_barrier(0); \
    __builtin_amdgcn_s_setprio(1); \
    _Pragma("unroll") for (int m2 = 0; m2 < 4; ++m2) \
      _Pragma("unroll") for (int n2 = 0; n2 < 2; ++n2) { \
        acc[(QM)*4+m2][(QN)*2+n2] = __builtin_amdgcn_mfma_f32_16x16x32_bf16( \
            aF[m2][0], BF[n2][0], acc[(QM)*4+m2][(QN)*2+n2], 0, 0, 0); \
        acc[(QM)*4+m2][(QN)*2+n2] = __builtin_amdgcn_mfma_f32_16x16x32_bf16( \
            aF[m2][1], BF[n2][1], acc[(QM)*4+m2][(QN)*2+n2], 0, 0, 0); } \
    __builtin_amdgcn_s_setprio(0); \
    __builtin_amdgcn_sched_barrier(0); \
  } while (0)

#define TILE(KT, DD) do { \
    const bool sA = (KT) + 1 < ktT; \
    const bool sB = (KT) + 2 < ktT; \
    /* P1 */ \
    RD_A(DD, 0); RD_B(DD, 0, bF0); \
    if (sA) STG_A((KT) + 1, 0); \
    asm volatile("s_waitcnt lgkmcnt(8)"); \
    __builtin_amdgcn_s_barrier(); \
    MM(0, 0, bF0); \
    __builtin_amdgcn_s_barrier(); \
    /* P2 */ \
    RD_B(DD, 1, bF1); \
    if (sA) STG_A((KT) + 1, 1); \
    __builtin_amdgcn_s_barrier(); \
    MM(0, 1, bF1); \
    __builtin_amdgcn_s_barrier(); \
    /* P3 */ \
    RD_A(DD, 1); \
    if (sB) STG_B((KT) + 2, 0); \
    __builtin_amdgcn_s_barrier(); \
    MM(1, 0, bF0); \
    __builtin_amdgcn_s_barrier(); \
    /* P4 */ \
    if (sB) STG_B((KT) + 2, 1); \
    MM(1, 1, bF1); \
    if ((KT) < ktT - 2) { asm volatile("s_waitcnt vmcnt(4)"); } \
    else                { asm volatile("s_waitcnt vmcnt(0)"); } \
    __builtin_amdgcn_sched_barrier(0); \
    __builtin_amdgcn_s_barrier(); \
  } while (0)

    const int ktT = K >> 6;   // 32

    // prologue: A(0) both halves, B(0) both halves, B(1) both halves; retire first 8
    STG_A(0, 0); STG_A(0, 1);
    STG_B(0, 0); STG_B(0, 1);
    STG_B(1, 0); STG_B(1, 1);
    asm volatile("s_waitcnt vmcnt(4)");
    __builtin_amdgcn_sched_barrier(0);
    __builtin_amdgcn_s_barrier();

    for (int kt = 0; kt < ktT; kt += 2) {
        TILE(kt, 0);
        TILE(kt + 1, 16384);
    }

#undef TILE
#undef MM
#undef RD_A
#undef RD_B
#undef STG_A
#undef STG_B

    // ---- epilogue: bias (+ RoPE for MODE 0 on cols < 4096), store
    #pragma unroll
    for (int mi = 0; mi < 8; ++mi) {
        #pragma unroll
        for (int ni = 0; ni < 4; ++ni) {
            #pragma unroll
            for (int j = 0; j < 4; ++j) {
                const int r  = m0 + wr * 128 + mi * 16 + fq * 4 + j;
                const int cg = n0 + wc * 64 + ni * 16 + fr;
                float v = acc[mi][ni][j];
                if (MODE == 0) {
                    v += (cg < 2048) ? b0[cg] : ((cg < 4096) ? b1[cg - 2048] : b2[cg - 4096]);
                    if (cg < 4096) {  // block-uniform: RoPE on Q and K
                        const int s = r & (SEQ - 1);
                        const int i = (cg >> 1) & 63;
                        const float cs = fcos[s * 64 + i];
                        const float sn = fsin[s * 64 + i];
                        const float p  = __shfl_xor(v, 1);
                        v = (fr & 1) ? (p * sn + v * cs) : (v * cs - p * sn);
                    }
                    ((unsigned short*)C)[(size_t)r * ldc + cg] = f2bf(v);
                } else {
                    v += b0[cg];
                    ((float*)C)[(size_t)r * ldc + cg] = v;
                }
            }
        }
    }
}

// ---------------- 128x128 GEMM core (small GEMMs) ----------------
template<int OUT_BF16, int HAS_BIAS>
__device__ __forceinline__ void gemm_tile_core(
    const unsigned short* __restrict__ A, int lda,
    const unsigned short* __restrict__ B, int ldb,
    const float* __restrict__ bias,
    void* __restrict__ Cptr, int ldc, int K)
{
    __shared__ __align__(16) unsigned short As[128 * 64];
    __shared__ __align__(16) unsigned short Bs[128 * 64];

    const int t  = threadIdx.x;
    const int l  = t & 63;
    const int w  = t >> 6;
    const int wr = w >> 1, wc = w & 1;
    const int fr = l & 15, fq = l >> 4;

    f32x4 acc[4][4] = {};

    const int srow = t >> 3;
    const int scol = (t & 7) * 8;

    for (int k0 = 0; k0 < K; k0 += 64) {
        __syncthreads();
        #pragma unroll
        for (int r = 0; r < 4; ++r) {
            gld_lds16(A + (size_t)(r * 32 + srow) * lda + k0 + scol, &As[(r * 32 + srow) * 64 + scol]);
            gld_lds16(B + (size_t)(r * 32 + srow) * ldb + k0 + scol, &Bs[(r * 32 + srow) * 64 + scol]);
        }
        __syncthreads();
        #pragma unroll
        for (int kk = 0; kk < 2; ++kk) {
            short8 a[4], b[4];
            #pragma unroll
            for (int mi = 0; mi < 4; ++mi)
                a[mi] = *(const short8*)&As[(wr * 64 + mi * 16 + fr) * 64 + kk * 32 + fq * 8];
            #pragma unroll
            for (int ni = 0; ni < 4; ++ni)
                b[ni] = *(const short8*)&Bs[(wc * 64 + ni * 16 + fr) * 64 + kk * 32 + fq * 8];
            #pragma unroll
            for (int mi = 0; mi < 4; ++mi)
                #pragma unroll
                for (int ni = 0; ni < 4; ++ni)
                    acc[mi][ni] = __builtin_amdgcn_mfma_f32_16x16x32_bf16(a[mi], b[ni], acc[mi][ni], 0, 0, 0);
        }
    }

    #pragma unroll
    for (int mi = 0; mi < 4; ++mi) {
        #pragma unroll
        for (int ni = 0; ni < 4; ++ni) {
            #pragma unroll
            for (int j = 0; j < 4; ++j) {
                int rr = wr * 64 + mi * 16 + fq * 4 + j;
                int cc = wc * 64 + ni * 16 + fr;
                float v = acc[mi][ni][j];
                if (HAS_BIAS) v += bias[cc];
                if (OUT_BF16) ((unsigned short*)Cptr)[(size_t)rr * ldc + cc] = f2bf(v);
                else          ((float*)Cptr)[(size_t)rr * ldc + cc] = v;
            }
        }
    }
}

// ---------------- K^T/V partials: part[bh][ks][d1][d2] = sum_s K[s][d1]*V[s][d2] ----------------
__global__ __launch_bounds__(256) void ktv_kernel(
    const unsigned short* __restrict__ QKV, float* __restrict__ part)
{
    const int ks = blockIdx.x;  // 0..7
    const int bh = blockIdx.y;  // 0..31
    const int b = bh >> 4, h = bh & 15;
    const unsigned short* Kbase = QKV + (size_t)(b * SEQ + ks * 256) * NQKV + 2048 + h * HD;
    const unsigned short* Vbase = QKV + (size_t)(b * SEQ + ks * 256) * NQKV + 4096 + h * HD;

    __shared__ __align__(16) unsigned short Ks_[64 * 128];
    __shared__ __align__(16) unsigned short Vs_[64 * 128];

    const int t  = threadIdx.x;
    const int l  = t & 63;
    const int w  = t >> 6;
    const int wr = w >> 1, wc = w & 1;
    const int fr = l & 15, fq = l >> 4;

    f32x4 acc[4][4] = {};

    const int srow = t >> 4;
    const int scol = (t & 15) * 8;

    for (int sc = 0; sc < 4; ++sc) {
        __syncthreads();
        #pragma unroll
        for (int r = 0; r < 4; ++r) {
            gld_lds16(Kbase + (size_t)(sc * 64 + r * 16 + srow) * NQKV + scol, &Ks_[(r * 16 + srow) * 128 + scol]);
            gld_lds16(Vbase + (size_t)(sc * 64 + r * 16 + srow) * NQKV + scol, &Vs_[(r * 16 + srow) * 128 + scol]);
        }
        __syncthreads();
        #pragma unroll
        for (int kk = 0; kk < 2; ++kk) {
            short8 a[4], bb[4];
            #pragma unroll
            for (int mi = 0; mi < 4; ++mi)      // A = K  (m index = d1)
                #pragma unroll
                for (int i = 0; i < 8; ++i)
                    a[mi][i] = (short)Ks_[(kk * 32 + fq * 8 + i) * 128 + wr * 64 + mi * 16 + fr];
            #pragma unroll
            for (int ni = 0; ni < 4; ++ni)      // B = V  (n index = d2)
                #pragma unroll
                for (int i = 0; i < 8; ++i)
                    bb[ni][i] = (short)Vs_[(kk * 32 + fq * 8 + i) * 128 + wc * 64 + ni * 16 + fr];
            #pragma unroll
            for (int mi = 0; mi < 4; ++mi)
                #pragma unroll
                for (int ni = 0; ni < 4; ++ni)
                    acc[mi][ni] = __builtin_amdgcn_mfma_f32_16x16x32_bf16(a[mi], bb[ni], acc[mi][ni], 0, 0, 0);
        }
    }

    float* base = part + ((size_t)bh * 8 + ks) * 16384;
    #pragma unroll
    for (int mi = 0; mi < 4; ++mi)
        #pragma unroll
        for (int ni = 0; ni < 4; ++ni)
            #pragma unroll
            for (int j = 0; j < 4; ++j)
                base[(wr * 64 + mi * 16 + fq * 4 + j) * 128 + wc * 64 + ni * 16 + fr] = acc[mi][ni][j];
}

// ---------------- reduce partials, scale, -> bf16 M2t[bh][d1][d2] ----------------
__global__ void ktv_reduce(const float* __restrict__ part, unsigned short* __restrict__ M2t) {
    int idx = blockIdx.x * 256 + threadIdx.x;
    int bh = idx >> 14, rem = idx & 16383;
    const float* p = part + ((size_t)bh * 8) * 16384 + rem;
    float s = 0.f;
    #pragma unroll
    for (int k = 0; k < 8; ++k) s += p[(size_t)k * 16384];
    M2t[idx] = f2bf(s * 0.08838834764831845f);  // 1/sqrt(128)
}

// ---------------- W2[b][i][h*128+d1] = sum_d2 Wo[i][h*128+d2] * M2t[bh][d1][d2] ----------------
__global__ __launch_bounds__(256) void w2_gemm(
    const unsigned short* __restrict__ Wo2, const unsigned short* __restrict__ M2t,
    unsigned short* __restrict__ W2)
{
    const int mt = blockIdx.x;   // 0..15
    const int bh = blockIdx.y;   // 0..31
    const int b = bh >> 4, h = bh & 15;
    const unsigned short* A = Wo2 + (size_t)(mt * 128) * DIMN + h * HD;
    const unsigned short* B = M2t + (size_t)bh * HD * HD;
    unsigned short* Cp = W2 + (size_t)b * DIMN * DIMN + (size_t)(mt * 128) * DIMN + h * HD;
    gemm_tile_core<1, 0>(A, DIMN, B, HD, nullptr, Cp, DIMN, HD);
}

extern "C" void kernel_launch(void* const* d_in, const int* in_sizes, int n_in,
                              void* d_out, int out_size, void* d_ws, size_t ws_size,
                              hipStream_t stream) {
    const float* x    = (const float*)d_in[0];
    const float* fcos = (const float*)d_in[1];
    const float* fsin = (const float*)d_in[2];
    const float* wq   = (const float*)d_in[3];
    const float* bq   = (const float*)d_in[4];
    const float* wk   = (const float*)d_in[5];
    const float* bk   = (const float*)d_in[6];
    const float* wv   = (const float*)d_in[7];
    const float* bv   = (const float*)d_in[8];
    const float* wo   = (const float*)d_in[9];
    const float* bo   = (const float*)d_in[10];
    float* out = (float*)d_out;

    char* ws = (char*)d_ws;
    size_t off = 0;
    auto alloc = [&](size_t bytes) { char* p = ws + off; off += (bytes + 255) & ~(size_t)255; return p; };

    unsigned short* Xb   = (unsigned short*)alloc((size_t)ROWS * DIMN * 2);
    unsigned short* Wcat = (unsigned short*)alloc((size_t)NQKV * DIMN * 2);
    unsigned short* Wo2  = (unsigned short*)alloc((size_t)DIMN * DIMN * 2);
    unsigned short* QKV  = (unsigned short*)alloc((size_t)ROWS * NQKV * 2);
    float*          part = (float*)alloc((size_t)32 * 8 * HD * HD * 4);
    unsigned short* M2t  = (unsigned short*)alloc((size_t)32 * HD * HD * 2);
    unsigned short* W2   = (unsigned short*)alloc((size_t)BSZ * DIMN * DIMN * 2);

    // all converts in one launch
    cvt_all<<<24576, 256, 0, stream>>>(x, wq, wk, wv, wo, Xb, Wcat, Wo2);

    // fused QKV projection + bias + RoPE  (M=4096, N=6144, K=2048): 16x24 = 384 blocks
    gemm256<0><<<384, 512, 0, stream>>>(
        Xb, DIMN, Wcat, DIMN, bq, bk, bv, fcos, fsin, QKV, NQKV, DIMN);

    // reassociated attention (no softmax): M2t = (K^T V)^T/sqrt(d) per (b,h)
    ktv_kernel<<<dim3(8, 32), 256, 0, stream>>>(QKV, part);
    ktv_reduce<<<(32 * 16384) / 256, 256, 0, stream>>>(part, M2t);

    // fold attention + output projection: W2_b = concat_h(Wo_h @ M2_{b,h})
    w2_gemm<<<dim3(16, 32), 256, 0, stream>>>(Wo2, M2t, W2);

    // out = Q @ W2_b^T + bo  (M=4096, N=2048, K=2048 per batch): 16x8 = 128 blocks
    gemm256<1><<<128, 512, 0, stream>>>(
        QKV, NQKV, W2, DIMN, bo, nullptr, nullptr, nullptr, nullptr, out, DIMN, DIMN);
}

// Round 7
// 243.412 us; speedup vs baseline: 2.5448x; 1.0147x over previous
//
#include <hip/hip_runtime.h>
#include <hip/hip_bf16.h>

#define DIMN 2048
#define NQKV 6144
#define NH 16
#define HD 128
#define BSZ 2
#define SEQ 2048
#define ROWS (BSZ*SEQ)   // 4096

typedef short short8 __attribute__((ext_vector_type(8)));
typedef float f32x4 __attribute__((ext_vector_type(4)));

__device__ __forceinline__ unsigned short f2bf(float f) {
    __hip_bfloat16 h = __float2bfloat16(f);
    unsigned short u; __builtin_memcpy(&u, &h, 2); return u;
}

__device__ __forceinline__ void gld_lds16(const void* g, void* l) {
    __builtin_amdgcn_global_load_lds(
        (const __attribute__((address_space(1))) void*)g,
        (__attribute__((address_space(3))) void*)l, 16, 0, 0);
}

// ---------------- fused f32 -> bf16 converts ----------------
__global__ void cvt_all(const float* __restrict__ x, const float* __restrict__ wq,
                        const float* __restrict__ wk, const float* __restrict__ wv,
                        const float* __restrict__ wo,
                        unsigned short* __restrict__ Xb, unsigned short* __restrict__ Wcat,
                        unsigned short* __restrict__ Wo2) {
    int bid = blockIdx.x;
    const float* in; unsigned short* out; int base;
    if      (bid <  8192) { in = x;  out = Xb;             base = bid; }
    else if (bid < 12288) { in = wq; out = Wcat;           base = bid - 8192; }
    else if (bid < 16384) { in = wk; out = Wcat + 4194304; base = bid - 12288; }
    else if (bid < 20480) { in = wv; out = Wcat + 8388608; base = bid - 16384; }
    else                  { in = wo; out = Wo2;            base = bid - 20480; }
    int i = (base * 256 + threadIdx.x) * 4;
    float4 v = *(const float4*)(in + i);
    ushort4 o; o.x = f2bf(v.x); o.y = f2bf(v.y); o.z = f2bf(v.z); o.w = f2bf(v.w);
    *(ushort4*)(out + i) = o;
}

// ================= 256x256 8-phase GEMM: C[m][n] = sum_k A[m][k]*B[n][k] ===========
// Engine identical to round 6 (verified: 0 bank conflicts, no spill, counted vmcnt).
// NEW: L2-aware XCD chunking. Theory: MODE0's old per-XCD co-resident set was 2m x 24n
// -> 24 MB of B through a 4 MB L2 (zero reuse, all from L3; aggregate staging demand
// 6.6 TB/s starves 256 CUs; the identical engine at 128 CUs (MODE1) ran 1.84x faster
// per block). New chunks: round1 8m x 4n per XCD (B=4MB fits L2, 8x reuse); round2 and
// MODE1 4m x 4n. Block->XCD binding assumed blockIdx%8 (same as r6 swizzle).

template<int MODE>
__global__ __launch_bounds__(512, 2) void gemm256(
    const unsigned short* __restrict__ A, int lda,
    const unsigned short* __restrict__ B, int ldb,
    const float* __restrict__ b0, const float* __restrict__ b1, const float* __restrict__ b2,
    const float* __restrict__ fcos, const float* __restrict__ fsin,
    void* __restrict__ C, int ldc, int K)
{
    __shared__ __align__(16) unsigned short As[32768];  // 64 KB: [2buf][2half][128][64]
    __shared__ __align__(16) unsigned short Bs[32768];  // 64 KB

    const int t  = threadIdx.x;
    const int l  = t & 63;
    const int w  = t >> 6;
    const int wr = w >> 2;          // 0..1
    const int wc = w & 3;           // 0..3
    const int fr = l & 15, fq = l >> 4;

    // ---- L2-aware chunked XCD swizzle ----
    const int xcd = blockIdx.x & 7;
    const int j   = blockIdx.x >> 3;
    int mt, nt;
    if (MODE == 0) {
        // 16 m-tiles x 24 n-tiles, 384 blocks, 48 j's per XCD.
        if (j < 32) {               // round 1: chunk 8m x 4n per XCD (B panel 4MB -> L2)
            mt = (xcd & 1) * 8 + (j >> 2);
            nt = (xcd >> 1) * 4 + (j & 3);
        } else {                    // round 2: 4 chunks (ng 4..5 x mg 0..1) split 4m x 4n
            const int p = j - 32, c = xcd >> 1;
            mt = (c & 1) * 8 + (xcd & 1) * 4 + (p >> 2);
            nt = (4 + (c >> 1)) * 4 + (p & 3);
        }
    } else {
        // 16 m-tiles x 8 n-tiles, 128 blocks: chunk 4m x 4n per XCD.
        mt = (xcd >> 1) * 4 + (j >> 2);
        nt = (xcd & 1) * 4 + (j & 3);
    }
    const int m0 = mt * 256;
    const int n0 = nt * 256;

    const unsigned short* Bsel = B;
    if (MODE == 1 && m0 >= 2048) Bsel += (size_t)2048 * 2048;  // per-batch W2

    // staging sources (pre-swizzled col; gld_lds dest linear)
    const int srow = t >> 3;                        // 0..63
    const int scol = ((t & 7) ^ (srow & 7)) * 8;
    const unsigned short* aS = A    + (size_t)(m0 + srow) * lda + scol;
    const unsigned short* bS = Bsel + (size_t)(n0 + srow) * ldb + scol;

#define STG_A(KT, H) do { \
    const unsigned short* s_ = aS + (size_t)(H) * 128 * lda + (size_t)(KT) * 64; \
    gld_lds16(s_,                    &As[(((KT) & 1) << 14) + ((H) << 13) + t * 8]); \
    gld_lds16(s_ + (size_t)64 * lda, &As[(((KT) & 1) << 14) + ((H) << 13) + 4096 + t * 8]); \
  } while (0)
#define STG_B(KT, H) do { \
    const unsigned short* s_ = bS + (size_t)(H) * 128 * ldb + (size_t)(KT) * 64; \
    gld_lds16(s_,                    &Bs[(((KT) & 1) << 14) + ((H) << 13) + t * 8]); \
    gld_lds16(s_ + (size_t)64 * ldb, &Bs[(((KT) & 1) << 14) + ((H) << 13) + 4096 + t * 8]); \
  } while (0)

    // reader offsets (swizzled; all row offsets %8==0 so key = fr&7)
    const int cK0 = (fq ^ (fr & 7)) * 8;
    const int cK1 = ((4 + fq) ^ (fr & 7)) * 8;
    const int aB0 = wr * 8192 + fr * 64;   // + qm*4096 + m2*1024
    const int bB0 = wc * 4096 + fr * 64;   // + qn*2048 + n2*1024

    short8 aF[4][2], bF0[2][2], bF1[2][2];
    f32x4  acc[8][4] = {};

#define RD_A(DD, QM) do { _Pragma("unroll") for (int m2 = 0; m2 < 4; ++m2) { \
    aF[m2][0] = *(const short8*)&As[(DD) + aB0 + (QM) * 4096 + m2 * 1024 + cK0]; \
    aF[m2][1] = *(const short8*)&As[(DD) + aB0 + (QM) * 4096 + m2 * 1024 + cK1]; } } while (0)
#define RD_B(DD, QN, BF) do { _Pragma("unroll") for (int n2 = 0; n2 < 2; ++n2) { \
    BF[n2][0] = *(const short8*)&Bs[(DD) + bB0 + (QN) * 2048 + n2 * 1024 + cK0]; \
    BF[n2][1] = *(const short8*)&Bs[(DD) + bB0 + (QN) * 2048 + n2 * 1024 + cK1]; } } while (0)

#define MM(QM, QN, BF) do { \
    asm volatile("s_waitcnt lgkmcnt(0)"); \
    __builtin_amdgcn_sched_barrier(0); \
    __builtin_amdgcn_s_setprio(1); \
    _Pragma("unroll") for (int m2 = 0; m2 < 4; ++m2) \
      _Pragma("unroll") for (int n2 = 0; n2 < 2; ++n2) { \
        acc[(QM)*4+m2][(QN)*2+n2] = __builtin_amdgcn_mfma_f32_16x16x32_bf16( \
            aF[m2][0], BF[n2][0], acc[(QM)*4+m2][(QN)*2+n2], 0, 0, 0); \
        acc[(QM)*4+m2][(QN)*2+n2] = __builtin_amdgcn_mfma_f32_16x16x32_bf16( \
            aF[m2][1], BF[n2][1], acc[(QM)*4+m2][(QN)*2+n2], 0, 0, 0); } \
    __builtin_amdgcn_s_setprio(0); \
    __builtin_amdgcn_sched_barrier(0); \
  } while (0)

#define TILE(KT, DD) do { \
    const bool sA = (KT) + 1 < ktT; \
    const bool sB = (KT) + 2 < ktT; \
    /* P1 */ \
    RD_A(DD, 0); RD_B(DD, 0, bF0); \
    if (sA) STG_A((KT) + 1, 0); \
    asm volatile("s_waitcnt lgkmcnt(8)"); \
    __builtin_amdgcn_s_barrier(); \
    MM(0, 0, bF0); \
    __builtin_amdgcn_s_barrier(); \
    /* P2 */ \
    RD_B(DD, 1, bF1); \
    if (sA) STG_A((KT) + 1, 1); \
    __builtin_amdgcn_s_barrier(); \
    MM(0, 1, bF1); \
    __builtin_amdgcn_s_barrier(); \
    /* P3 */ \
    RD_A(DD, 1); \
    if (sB) STG_B((KT) + 2, 0); \
    __builtin_amdgcn_s_barrier(); \
    MM(1, 0, bF0); \
    __builtin_amdgcn_s_barrier(); \
    /* P4 */ \
    if (sB) STG_B((KT) + 2, 1); \
    MM(1, 1, bF1); \
    if ((KT) < ktT - 2) { asm volatile("s_waitcnt vmcnt(4)"); } \
    else                { asm volatile("s_waitcnt vmcnt(0)"); } \
    __builtin_amdgcn_sched_barrier(0); \
    __builtin_amdgcn_s_barrier(); \
  } while (0)

    const int ktT = K >> 6;   // 32

    // prologue: A(0), B(0), B(1); retire first 8 loads
    STG_A(0, 0); STG_A(0, 1);
    STG_B(0, 0); STG_B(0, 1);
    STG_B(1, 0); STG_B(1, 1);
    asm volatile("s_waitcnt vmcnt(4)");
    __builtin_amdgcn_sched_barrier(0);
    __builtin_amdgcn_s_barrier();

    for (int kt = 0; kt < ktT; kt += 2) {
        TILE(kt, 0);
        TILE(kt + 1, 16384);
    }

#undef TILE
#undef MM
#undef RD_A
#undef RD_B
#undef STG_A
#undef STG_B

    // ---- epilogue: bias (+ RoPE for MODE 0 on cols < 4096), store
    #pragma unroll
    for (int mi = 0; mi < 8; ++mi) {
        #pragma unroll
        for (int ni = 0; ni < 4; ++ni) {
            #pragma unroll
            for (int j2 = 0; j2 < 4; ++j2) {
                const int r  = m0 + wr * 128 + mi * 16 + fq * 4 + j2;
                const int cg = n0 + wc * 64 + ni * 16 + fr;
                float v = acc[mi][ni][j2];
                if (MODE == 0) {
                    v += (cg < 2048) ? b0[cg] : ((cg < 4096) ? b1[cg - 2048] : b2[cg - 4096]);
                    if (cg < 4096) {  // block-uniform: RoPE on Q and K
                        const int s = r & (SEQ - 1);
                        const int i = (cg >> 1) & 63;
                        const float cs = fcos[s * 64 + i];
                        const float sn = fsin[s * 64 + i];
                        const float p  = __shfl_xor(v, 1);
                        v = (fr & 1) ? (p * sn + v * cs) : (v * cs - p * sn);
                    }
                    ((unsigned short*)C)[(size_t)r * ldc + cg] = f2bf(v);
                } else {
                    v += b0[cg];
                    ((float*)C)[(size_t)r * ldc + cg] = v;
                }
            }
        }
    }
}

// ---------------- 128x128 GEMM core (small GEMMs) ----------------
template<int OUT_BF16, int HAS_BIAS>
__device__ __forceinline__ void gemm_tile_core(
    const unsigned short* __restrict__ A, int lda,
    const unsigned short* __restrict__ B, int ldb,
    const float* __restrict__ bias,
    void* __restrict__ Cptr, int ldc, int K)
{
    __shared__ __align__(16) unsigned short As[128 * 64];
    __shared__ __align__(16) unsigned short Bs[128 * 64];

    const int t  = threadIdx.x;
    const int l  = t & 63;
    const int w  = t >> 6;
    const int wr = w >> 1, wc = w & 1;
    const int fr = l & 15, fq = l >> 4;

    f32x4 acc[4][4] = {};

    const int srow = t >> 3;
    const int scol = (t & 7) * 8;

    for (int k0 = 0; k0 < K; k0 += 64) {
        __syncthreads();
        #pragma unroll
        for (int r = 0; r < 4; ++r) {
            gld_lds16(A + (size_t)(r * 32 + srow) * lda + k0 + scol, &As[(r * 32 + srow) * 64 + scol]);
            gld_lds16(B + (size_t)(r * 32 + srow) * ldb + k0 + scol, &Bs[(r * 32 + srow) * 64 + scol]);
        }
        __syncthreads();
        #pragma unroll
        for (int kk = 0; kk < 2; ++kk) {
            short8 a[4], b[4];
            #pragma unroll
            for (int mi = 0; mi < 4; ++mi)
                a[mi] = *(const short8*)&As[(wr * 64 + mi * 16 + fr) * 64 + kk * 32 + fq * 8];
            #pragma unroll
            for (int ni = 0; ni < 4; ++ni)
                b[ni] = *(const short8*)&Bs[(wc * 64 + ni * 16 + fr) * 64 + kk * 32 + fq * 8];
            #pragma unroll
            for (int mi = 0; mi < 4; ++mi)
                #pragma unroll
                for (int ni = 0; ni < 4; ++ni)
                    acc[mi][ni] = __builtin_amdgcn_mfma_f32_16x16x32_bf16(a[mi], b[ni], acc[mi][ni], 0, 0, 0);
        }
    }

    #pragma unroll
    for (int mi = 0; mi < 4; ++mi) {
        #pragma unroll
        for (int ni = 0; ni < 4; ++ni) {
            #pragma unroll
            for (int j = 0; j < 4; ++j) {
                int rr = wr * 64 + mi * 16 + fq * 4 + j;
                int cc = wc * 64 + ni * 16 + fr;
                float v = acc[mi][ni][j];
                if (HAS_BIAS) v += bias[cc];
                if (OUT_BF16) ((unsigned short*)Cptr)[(size_t)rr * ldc + cc] = f2bf(v);
                else          ((float*)Cptr)[(size_t)rr * ldc + cc] = v;
            }
        }
    }
}

// ---------------- K^T/V partials: part[bh][ks][d1][d2] = sum_s K[s][d1]*V[s][d2] ----------------
__global__ __launch_bounds__(256) void ktv_kernel(
    const unsigned short* __restrict__ QKV, float* __restrict__ part)
{
    const int ks = blockIdx.x;  // 0..7
    const int bh = blockIdx.y;  // 0..31
    const int b = bh >> 4, h = bh & 15;
    const unsigned short* Kbase = QKV + (size_t)(b * SEQ + ks * 256) * NQKV + 2048 + h * HD;
    const unsigned short* Vbase = QKV + (size_t)(b * SEQ + ks * 256) * NQKV + 4096 + h * HD;

    __shared__ __align__(16) unsigned short Ks_[64 * 128];
    __shared__ __align__(16) unsigned short Vs_[64 * 128];

    const int t  = threadIdx.x;
    const int l  = t & 63;
    const int w  = t >> 6;
    const int wr = w >> 1, wc = w & 1;
    const int fr = l & 15, fq = l >> 4;

    f32x4 acc[4][4] = {};

    const int srow = t >> 4;
    const int scol = (t & 15) * 8;

    for (int sc = 0; sc < 4; ++sc) {
        __syncthreads();
        #pragma unroll
        for (int r = 0; r < 4; ++r) {
            gld_lds16(Kbase + (size_t)(sc * 64 + r * 16 + srow) * NQKV + scol, &Ks_[(r * 16 + srow) * 128 + scol]);
            gld_lds16(Vbase + (size_t)(sc * 64 + r * 16 + srow) * NQKV + scol, &Vs_[(r * 16 + srow) * 128 + scol]);
        }
        __syncthreads();
        #pragma unroll
        for (int kk = 0; kk < 2; ++kk) {
            short8 a[4], bb[4];
            #pragma unroll
            for (int mi = 0; mi < 4; ++mi)      // A = K  (m index = d1)
                #pragma unroll
                for (int i = 0; i < 8; ++i)
                    a[mi][i] = (short)Ks_[(kk * 32 + fq * 8 + i) * 128 + wr * 64 + mi * 16 + fr];
            #pragma unroll
            for (int ni = 0; ni < 4; ++ni)      // B = V  (n index = d2)
                #pragma unroll
                for (int i = 0; i < 8; ++i)
                    bb[ni][i] = (short)Vs_[(kk * 32 + fq * 8 + i) * 128 + wc * 64 + ni * 16 + fr];
            #pragma unroll
            for (int mi = 0; mi < 4; ++mi)
                #pragma unroll
                for (int ni = 0; ni < 4; ++ni)
                    acc[mi][ni] = __builtin_amdgcn_mfma_f32_16x16x32_bf16(a[mi], bb[ni], acc[mi][ni], 0, 0, 0);
        }
    }

    float* base = part + ((size_t)bh * 8 + ks) * 16384;
    #pragma unroll
    for (int mi = 0; mi < 4; ++mi)
        #pragma unroll
        for (int ni = 0; ni < 4; ++ni)
            #pragma unroll
            for (int j = 0; j < 4; ++j)
                base[(wr * 64 + mi * 16 + fq * 4 + j) * 128 + wc * 64 + ni * 16 + fr] = acc[mi][ni][j];
}

// ---------------- reduce partials, scale, -> bf16 M2t[bh][d1][d2] ----------------
__global__ void ktv_reduce(const float* __restrict__ part, unsigned short* __restrict__ M2t) {
    int idx = blockIdx.x * 256 + threadIdx.x;
    int bh = idx >> 14, rem = idx & 16383;
    const float* p = part + ((size_t)bh * 8) * 16384 + rem;
    float s = 0.f;
    #pragma unroll
    for (int k = 0; k < 8; ++k) s += p[(size_t)k * 16384];
    M2t[idx] = f2bf(s * 0.08838834764831845f);  // 1/sqrt(128)
}

// ---------------- W2[b][i][h*128+d1] = sum_d2 Wo[i][h*128+d2] * M2t[bh][d1][d2] ----------------
__global__ __launch_bounds__(256) void w2_gemm(
    const unsigned short* __restrict__ Wo2, const unsigned short* __restrict__ M2t,
    unsigned short* __restrict__ W2)
{
    const int mt = blockIdx.x;   // 0..15
    const int bh = blockIdx.y;   // 0..31
    const int b = bh >> 4, h = bh & 15;
    const unsigned short* A = Wo2 + (size_t)(mt * 128) * DIMN + h * HD;
    const unsigned short* B = M2t + (size_t)bh * HD * HD;
    unsigned short* Cp = W2 + (size_t)b * DIMN * DIMN + (size_t)(mt * 128) * DIMN + h * HD;
    gemm_tile_core<1, 0>(A, DIMN, B, HD, nullptr, Cp, DIMN, HD);
}

extern "C" void kernel_launch(void* const* d_in, const int* in_sizes, int n_in,
                              void* d_out, int out_size, void* d_ws, size_t ws_size,
                              hipStream_t stream) {
    const float* x    = (const float*)d_in[0];
    const float* fcos = (const float*)d_in[1];
    const float* fsin = (const float*)d_in[2];
    const float* wq   = (const float*)d_in[3];
    const float* bq   = (const float*)d_in[4];
    const float* wk   = (const float*)d_in[5];
    const float* bk   = (const float*)d_in[6];
    const float* wv   = (const float*)d_in[7];
    const float* bv   = (const float*)d_in[8];
    const float* wo   = (const float*)d_in[9];
    const float* bo   = (const float*)d_in[10];
    float* out = (float*)d_out;

    char* ws = (char*)d_ws;
    size_t off = 0;
    auto alloc = [&](size_t bytes) { char* p = ws + off; off += (bytes + 255) & ~(size_t)255; return p; };

    unsigned short* Xb   = (unsigned short*)alloc((size_t)ROWS * DIMN * 2);
    unsigned short* Wcat = (unsigned short*)alloc((size_t)NQKV * DIMN * 2);
    unsigned short* Wo2  = (unsigned short*)alloc((size_t)DIMN * DIMN * 2);
    unsigned short* QKV  = (unsigned short*)alloc((size_t)ROWS * NQKV * 2);
    float*          part = (float*)alloc((size_t)32 * 8 * HD * HD * 4);
    unsigned short* M2t  = (unsigned short*)alloc((size_t)32 * HD * HD * 2);
    unsigned short* W2   = (unsigned short*)alloc((size_t)BSZ * DIMN * DIMN * 2);

    // all converts in one launch
    cvt_all<<<24576, 256, 0, stream>>>(x, wq, wk, wv, wo, Xb, Wcat, Wo2);

    // fused QKV projection + bias + RoPE  (M=4096, N=6144, K=2048): 384 blocks
    gemm256<0><<<384, 512, 0, stream>>>(
        Xb, DIMN, Wcat, DIMN, bq, bk, bv, fcos, fsin, QKV, NQKV, DIMN);

    // reassociated attention (no softmax): M2t = (K^T V)^T/sqrt(d) per (b,h)
    ktv_kernel<<<dim3(8, 32), 256, 0, stream>>>(QKV, part);
    ktv_reduce<<<(32 * 16384) / 256, 256, 0, stream>>>(part, M2t);

    // fold attention + output projection: W2_b = concat_h(Wo_h @ M2_{b,h})
    w2_gemm<<<dim3(16, 32), 256, 0, stream>>>(Wo2, M2t, W2);

    // out = Q @ W2_b^T + bo  (M=4096, N=2048 per batch, K=2048): 128 blocks
    gemm256<1><<<128, 512, 0, stream>>>(
        QKV, NQKV, W2, DIMN, bo, nullptr, nullptr, nullptr, nullptr, out, DIMN, DIMN);
}

// Round 8
// 242.688 us; speedup vs baseline: 2.5524x; 1.0030x over previous
//
#include <hip/hip_runtime.h>
#include <hip/hip_bf16.h>

#define DIMN 2048
#define NQKV 6144
#define NH 16
#define HD 128
#define BSZ 2
#define SEQ 2048
#define ROWS (BSZ*SEQ)   // 4096

typedef short short8 __attribute__((ext_vector_type(8)));
typedef float f32x4 __attribute__((ext_vector_type(4)));

__device__ __forceinline__ unsigned short f2bf(float f) {
    __hip_bfloat16 h = __float2bfloat16(f);
    unsigned short u; __builtin_memcpy(&u, &h, 2); return u;
}

__device__ __forceinline__ void gld_lds16(const void* g, void* l) {
    __builtin_amdgcn_global_load_lds(
        (const __attribute__((address_space(1))) void*)g,
        (__attribute__((address_space(3))) void*)l, 16, 0, 0);
}

// ---------------- fused f32 -> bf16 converts ----------------
__global__ void cvt_all(const float* __restrict__ x, const float* __restrict__ wq,
                        const float* __restrict__ wk, const float* __restrict__ wv,
                        const float* __restrict__ wo,
                        unsigned short* __restrict__ Xb, unsigned short* __restrict__ Wcat,
                        unsigned short* __restrict__ Wo2) {
    int bid = blockIdx.x;
    const float* in; unsigned short* out; int base;
    if      (bid <  8192) { in = x;  out = Xb;             base = bid; }
    else if (bid < 12288) { in = wq; out = Wcat;           base = bid - 8192; }
    else if (bid < 16384) { in = wk; out = Wcat + 4194304; base = bid - 12288; }
    else if (bid < 20480) { in = wv; out = Wcat + 8388608; base = bid - 16384; }
    else                  { in = wo; out = Wo2;            base = bid - 20480; }
    int i = (base * 256 + threadIdx.x) * 4;
    float4 v = *(const float4*)(in + i);
    ushort4 o; o.x = f2bf(v.x); o.y = f2bf(v.y); o.z = f2bf(v.z); o.w = f2bf(v.w);
    *(ushort4*)(out + i) = o;
}

// ================= 256x256 8-phase GEMM: C[m][n] = sum_k A[m][k]*B[n][k] ===========
// r8 change (single variable): LDS reads are now INLINE-ASM ds_read_b128 with literal
// offset: immediates on precomputed 32-bit LDS addresses. Theory: pointer-based LDS reads
// force the compiler to insert its own vmcnt waits ordering them vs global_load_lds (an
// LDS-writing op it can't alias-analyze) -> per-phase drain (m218-V1 regime, =656 TF).
// Asm reads are invisible to alias analysis; ordering is ONLY my asm waits + barriers.
// Barriers carry "memory" clobber so gld_lds intrinsics cannot hoist across them.
// Geometry/grid/chunking identical to r7 (verified: 0 conflicts, no spill, FETCH=86MB).

template<int MODE>
__global__ __launch_bounds__(512, 2) void gemm256(
    const unsigned short* __restrict__ A, int lda,
    const unsigned short* __restrict__ B, int ldb,
    const float* __restrict__ b0, const float* __restrict__ b1, const float* __restrict__ b2,
    const float* __restrict__ fcos, const float* __restrict__ fsin,
    void* __restrict__ C, int ldc, int K)
{
    __shared__ __align__(16) unsigned short As[32768];  // 64 KB: [2buf][2half][128][64]
    __shared__ __align__(16) unsigned short Bs[32768];  // 64 KB

    const int t  = threadIdx.x;
    const int l  = t & 63;
    const int w  = t >> 6;
    const int wr = w >> 2;          // 0..1
    const int wc = w & 3;           // 0..3
    const int fr = l & 15, fq = l >> 4;

    // ---- L2-aware chunked XCD swizzle (unchanged from r7) ----
    const int xcd = blockIdx.x & 7;
    const int j   = blockIdx.x >> 3;
    int mt, nt;
    if (MODE == 0) {
        if (j < 32) {               // round 1: chunk 8m x 4n per XCD
            mt = (xcd & 1) * 8 + (j >> 2);
            nt = (xcd >> 1) * 4 + (j & 3);
        } else {                    // round 2: split 4m x 4n
            const int p = j - 32, c = xcd >> 1;
            mt = (c & 1) * 8 + (xcd & 1) * 4 + (p >> 2);
            nt = (4 + (c >> 1)) * 4 + (p & 3);
        }
    } else {
        mt = (xcd >> 1) * 4 + (j >> 2);
        nt = (xcd & 1) * 4 + (j & 3);
    }
    const int m0 = mt * 256;
    const int n0 = nt * 256;

    const unsigned short* Bsel = B;
    if (MODE == 1 && m0 >= 2048) Bsel += (size_t)2048 * 2048;  // per-batch W2

    // staging sources (pre-swizzled col; gld_lds dest linear)
    const int srow = t >> 3;                        // 0..63
    const int scol = ((t & 7) ^ (srow & 7)) * 8;
    const unsigned short* aS = A    + (size_t)(m0 + srow) * lda + scol;
    const unsigned short* bS = Bsel + (size_t)(n0 + srow) * ldb + scol;

#define STG_A(KT, H) do { \
    const unsigned short* s_ = aS + (size_t)(H) * 128 * lda + (size_t)(KT) * 64; \
    gld_lds16(s_,                    &As[(((KT) & 1) << 14) + ((H) << 13) + t * 8]); \
    gld_lds16(s_ + (size_t)64 * lda, &As[(((KT) & 1) << 14) + ((H) << 13) + 4096 + t * 8]); \
  } while (0)
#define STG_B(KT, H) do { \
    const unsigned short* s_ = bS + (size_t)(H) * 128 * ldb + (size_t)(KT) * 64; \
    gld_lds16(s_,                    &Bs[(((KT) & 1) << 14) + ((H) << 13) + t * 8]); \
    gld_lds16(s_ + (size_t)64 * ldb, &Bs[(((KT) & 1) << 14) + ((H) << 13) + 4096 + t * 8]); \
  } while (0)

    // reader offsets (swizzled; all row offsets %8==0 so key = fr&7), as 32-bit LDS addrs
    const int cK0 = (fq ^ (fr & 7)) * 8;
    const int cK1 = ((4 + fq) ^ (fr & 7)) * 8;
    const int aB0 = wr * 8192 + fr * 64;   // elements; + qm*4096 + m2*1024
    const int bB0 = wc * 4096 + fr * 64;   // elements; + qn*2048 + n2*1024

    const unsigned aA0 = (unsigned)(size_t)&As[aB0 + cK0];
    const unsigned aA1 = (unsigned)(size_t)&As[aB0 + cK1];
    const unsigned bA0 = (unsigned)(size_t)&Bs[bB0 + cK0];
    const unsigned bA1 = (unsigned)(size_t)&Bs[bB0 + cK1];

    short8 aF[4][2], bF0[2][2], bF1[2][2];
    f32x4  acc[8][4] = {};

// inline-asm ds_read_b128: invisible to compiler alias analysis (no implicit vmcnt waits)
#define DSR(dst, areg, OFF) \
    asm volatile("ds_read_b128 %0, %1 offset:%2" : "=v"(dst) : "v"(areg), "n"(OFF))

// byte offsets: buffer DDB in {0,32768}; QM*8192, m2*2048 (A); QN*4096, n2*2048 (B)
#define RD_A(DDB, QM) do { \
    DSR(aF[0][0], aA0, (DDB) + (QM) * 8192 + 0);    DSR(aF[0][1], aA1, (DDB) + (QM) * 8192 + 0); \
    DSR(aF[1][0], aA0, (DDB) + (QM) * 8192 + 2048); DSR(aF[1][1], aA1, (DDB) + (QM) * 8192 + 2048); \
    DSR(aF[2][0], aA0, (DDB) + (QM) * 8192 + 4096); DSR(aF[2][1], aA1, (DDB) + (QM) * 8192 + 4096); \
    DSR(aF[3][0], aA0, (DDB) + (QM) * 8192 + 6144); DSR(aF[3][1], aA1, (DDB) + (QM) * 8192 + 6144); \
  } while (0)
#define RD_B(DDB, QN, BF) do { \
    DSR(BF[0][0], bA0, (DDB) + (QN) * 4096 + 0);    DSR(BF[0][1], bA1, (DDB) + (QN) * 4096 + 0); \
    DSR(BF[1][0], bA0, (DDB) + (QN) * 4096 + 2048); DSR(BF[1][1], bA1, (DDB) + (QN) * 4096 + 2048); \
  } while (0)

#define BAR() asm volatile("s_barrier" ::: "memory")

#define MM(QM, QN, BF) do { \
    asm volatile("s_waitcnt lgkmcnt(0)"); \
    __builtin_amdgcn_sched_barrier(0); \
    __builtin_amdgcn_s_setprio(1); \
    _Pragma("unroll") for (int m2 = 0; m2 < 4; ++m2) \
      _Pragma("unroll") for (int n2 = 0; n2 < 2; ++n2) { \
        acc[(QM)*4+m2][(QN)*2+n2] = __builtin_amdgcn_mfma_f32_16x16x32_bf16( \
            aF[m2][0], BF[n2][0], acc[(QM)*4+m2][(QN)*2+n2], 0, 0, 0); \
        acc[(QM)*4+m2][(QN)*2+n2] = __builtin_amdgcn_mfma_f32_16x16x32_bf16( \
            aF[m2][1], BF[n2][1], acc[(QM)*4+m2][(QN)*2+n2], 0, 0, 0); } \
    __builtin_amdgcn_s_setprio(0); \
    __builtin_amdgcn_sched_barrier(0); \
  } while (0)

#define TILE(KT, DDB) do { \
    const bool sA = (KT) + 1 < ktT; \
    const bool sB = (KT) + 2 < ktT; \
    /* P1 */ \
    RD_A(DDB, 0); RD_B(DDB, 0, bF0); \
    if (sA) STG_A((KT) + 1, 0); \
    asm volatile("s_waitcnt lgkmcnt(8)"); \
    BAR(); \
    MM(0, 0, bF0); \
    BAR(); \
    /* P2 */ \
    RD_B(DDB, 1, bF1); \
    if (sA) STG_A((KT) + 1, 1); \
    BAR(); \
    MM(0, 1, bF1); \
    BAR(); \
    /* P3 */ \
    RD_A(DDB, 1); \
    if (sB) STG_B((KT) + 2, 0); \
    BAR(); \
    MM(1, 0, bF0); \
    BAR(); \
    /* P4 */ \
    if (sB) STG_B((KT) + 2, 1); \
    MM(1, 1, bF1); \
    if ((KT) < ktT - 2) { asm volatile("s_waitcnt vmcnt(4)"); } \
    else                { asm volatile("s_waitcnt vmcnt(0)"); } \
    __builtin_amdgcn_sched_barrier(0); \
    BAR(); \
  } while (0)

    const int ktT = K >> 6;   // 32

    // prologue: A(0), B(0), B(1); retire first 8 loads (leave B(1)'s 4 in flight)
    STG_A(0, 0); STG_A(0, 1);
    STG_B(0, 0); STG_B(0, 1);
    STG_B(1, 0); STG_B(1, 1);
    asm volatile("s_waitcnt vmcnt(4)");
    __builtin_amdgcn_sched_barrier(0);
    BAR();

    for (int kt = 0; kt < ktT; kt += 2) {
        TILE(kt, 0);
        TILE(kt + 1, 32768);
    }

#undef TILE
#undef MM
#undef BAR
#undef RD_A
#undef RD_B
#undef DSR
#undef STG_A
#undef STG_B

    // ---- epilogue: bias (+ RoPE for MODE 0 on cols < 4096), store
    #pragma unroll
    for (int mi = 0; mi < 8; ++mi) {
        #pragma unroll
        for (int ni = 0; ni < 4; ++ni) {
            #pragma unroll
            for (int j2 = 0; j2 < 4; ++j2) {
                const int r  = m0 + wr * 128 + mi * 16 + fq * 4 + j2;
                const int cg = n0 + wc * 64 + ni * 16 + fr;
                float v = acc[mi][ni][j2];
                if (MODE == 0) {
                    v += (cg < 2048) ? b0[cg] : ((cg < 4096) ? b1[cg - 2048] : b2[cg - 4096]);
                    if (cg < 4096) {  // block-uniform: RoPE on Q and K
                        const int s = r & (SEQ - 1);
                        const int i = (cg >> 1) & 63;
                        const float cs = fcos[s * 64 + i];
                        const float sn = fsin[s * 64 + i];
                        const float p  = __shfl_xor(v, 1);
                        v = (fr & 1) ? (p * sn + v * cs) : (v * cs - p * sn);
                    }
                    ((unsigned short*)C)[(size_t)r * ldc + cg] = f2bf(v);
                } else {
                    v += b0[cg];
                    ((float*)C)[(size_t)r * ldc + cg] = v;
                }
            }
        }
    }
}

// ---------------- 128x128 GEMM core (small GEMMs) ----------------
template<int OUT_BF16, int HAS_BIAS>
__device__ __forceinline__ void gemm_tile_core(
    const unsigned short* __restrict__ A, int lda,
    const unsigned short* __restrict__ B, int ldb,
    const float* __restrict__ bias,
    void* __restrict__ Cptr, int ldc, int K)
{
    __shared__ __align__(16) unsigned short As[128 * 64];
    __shared__ __align__(16) unsigned short Bs[128 * 64];

    const int t  = threadIdx.x;
    const int l  = t & 63;
    const int w  = t >> 6;
    const int wr = w >> 1, wc = w & 1;
    const int fr = l & 15, fq = l >> 4;

    f32x4 acc[4][4] = {};

    const int srow = t >> 3;
    const int scol = (t & 7) * 8;

    for (int k0 = 0; k0 < K; k0 += 64) {
        __syncthreads();
        #pragma unroll
        for (int r = 0; r < 4; ++r) {
            gld_lds16(A + (size_t)(r * 32 + srow) * lda + k0 + scol, &As[(r * 32 + srow) * 64 + scol]);
            gld_lds16(B + (size_t)(r * 32 + srow) * ldb + k0 + scol, &Bs[(r * 32 + srow) * 64 + scol]);
        }
        __syncthreads();
        #pragma unroll
        for (int kk = 0; kk < 2; ++kk) {
            short8 a[4], b[4];
            #pragma unroll
            for (int mi = 0; mi < 4; ++mi)
                a[mi] = *(const short8*)&As[(wr * 64 + mi * 16 + fr) * 64 + kk * 32 + fq * 8];
            #pragma unroll
            for (int ni = 0; ni < 4; ++ni)
                b[ni] = *(const short8*)&Bs[(wc * 64 + ni * 16 + fr) * 64 + kk * 32 + fq * 8];
            #pragma unroll
            for (int mi = 0; mi < 4; ++mi)
                #pragma unroll
                for (int ni = 0; ni < 4; ++ni)
                    acc[mi][ni] = __builtin_amdgcn_mfma_f32_16x16x32_bf16(a[mi], b[ni], acc[mi][ni], 0, 0, 0);
        }
    }

    #pragma unroll
    for (int mi = 0; mi < 4; ++mi) {
        #pragma unroll
        for (int ni = 0; ni < 4; ++ni) {
            #pragma unroll
            for (int j = 0; j < 4; ++j) {
                int rr = wr * 64 + mi * 16 + fq * 4 + j;
                int cc = wc * 64 + ni * 16 + fr;
                float v = acc[mi][ni][j];
                if (HAS_BIAS) v += bias[cc];
                if (OUT_BF16) ((unsigned short*)Cptr)[(size_t)rr * ldc + cc] = f2bf(v);
                else          ((float*)Cptr)[(size_t)rr * ldc + cc] = v;
            }
        }
    }
}

// ---------------- K^T/V partials: part[bh][ks][d1][d2] = sum_s K[s][d1]*V[s][d2] ----------------
__global__ __launch_bounds__(256) void ktv_kernel(
    const unsigned short* __restrict__ QKV, float* __restrict__ part)
{
    const int ks = blockIdx.x;  // 0..7
    const int bh = blockIdx.y;  // 0..31
    const int b = bh >> 4, h = bh & 15;
    const unsigned short* Kbase = QKV + (size_t)(b * SEQ + ks * 256) * NQKV + 2048 + h * HD;
    const unsigned short* Vbase = QKV + (size_t)(b * SEQ + ks * 256) * NQKV + 4096 + h * HD;

    __shared__ __align__(16) unsigned short Ks_[64 * 128];
    __shared__ __align__(16) unsigned short Vs_[64 * 128];

    const int t  = threadIdx.x;
    const int l  = t & 63;
    const int w  = t >> 6;
    const int wr = w >> 1, wc = w & 1;
    const int fr = l & 15, fq = l >> 4;

    f32x4 acc[4][4] = {};

    const int srow = t >> 4;
    const int scol = (t & 15) * 8;

    for (int sc = 0; sc < 4; ++sc) {
        __syncthreads();
        #pragma unroll
        for (int r = 0; r < 4; ++r) {
            gld_lds16(Kbase + (size_t)(sc * 64 + r * 16 + srow) * NQKV + scol, &Ks_[(r * 16 + srow) * 128 + scol]);
            gld_lds16(Vbase + (size_t)(sc * 64 + r * 16 + srow) * NQKV + scol, &Vs_[(r * 16 + srow) * 128 + scol]);
        }
        __syncthreads();
        #pragma unroll
        for (int kk = 0; kk < 2; ++kk) {
            short8 a[4], bb[4];
            #pragma unroll
            for (int mi = 0; mi < 4; ++mi)      // A = K  (m index = d1)
                #pragma unroll
                for (int i = 0; i < 8; ++i)
                    a[mi][i] = (short)Ks_[(kk * 32 + fq * 8 + i) * 128 + wr * 64 + mi * 16 + fr];
            #pragma unroll
            for (int ni = 0; ni < 4; ++ni)      // B = V  (n index = d2)
                #pragma unroll
                for (int i = 0; i < 8; ++i)
                    bb[ni][i] = (short)Vs_[(kk * 32 + fq * 8 + i) * 128 + wc * 64 + ni * 16 + fr];
            #pragma unroll
            for (int mi = 0; mi < 4; ++mi)
                #pragma unroll
                for (int ni = 0; ni < 4; ++ni)
                    acc[mi][ni] = __builtin_amdgcn_mfma_f32_16x16x32_bf16(a[mi], bb[ni], acc[mi][ni], 0, 0, 0);
        }
    }

    float* base = part + ((size_t)bh * 8 + ks) * 16384;
    #pragma unroll
    for (int mi = 0; mi < 4; ++mi)
        #pragma unroll
        for (int ni = 0; ni < 4; ++ni)
            #pragma unroll
            for (int j = 0; j < 4; ++j)
                base[(wr * 64 + mi * 16 + fq * 4 + j) * 128 + wc * 64 + ni * 16 + fr] = acc[mi][ni][j];
}

// ---------------- reduce partials, scale, -> bf16 M2t[bh][d1][d2] ----------------
__global__ void ktv_reduce(const float* __restrict__ part, unsigned short* __restrict__ M2t) {
    int idx = blockIdx.x * 256 + threadIdx.x;
    int bh = idx >> 14, rem = idx & 16383;
    const float* p = part + ((size_t)bh * 8) * 16384 + rem;
    float s = 0.f;
    #pragma unroll
    for (int k = 0; k < 8; ++k) s += p[(size_t)k * 16384];
    M2t[idx] = f2bf(s * 0.08838834764831845f);  // 1/sqrt(128)
}

// ---------------- W2[b][i][h*128+d1] = sum_d2 Wo[i][h*128+d2] * M2t[bh][d1][d2] ----------------
__global__ __launch_bounds__(256) void w2_gemm(
    const unsigned short* __restrict__ Wo2, const unsigned short* __restrict__ M2t,
    unsigned short* __restrict__ W2)
{
    const int mt = blockIdx.x;   // 0..15
    const int bh = blockIdx.y;   // 0..31
    const int b = bh >> 4, h = bh & 15;
    const unsigned short* A = Wo2 + (size_t)(mt * 128) * DIMN + h * HD;
    const unsigned short* B = M2t + (size_t)bh * HD * HD;
    unsigned short* Cp = W2 + (size_t)b * DIMN * DIMN + (size_t)(mt * 128) * DIMN + h * HD;
    gemm_tile_core<1, 0>(A, DIMN, B, HD, nullptr, Cp, DIMN, HD);
}

extern "C" void kernel_launch(void* const* d_in, const int* in_sizes, int n_in,
                              void* d_out, int out_size, void* d_ws, size_t ws_size,
                              hipStream_t stream) {
    const float* x    = (const float*)d_in[0];
    const float* fcos = (const float*)d_in[1];
    const float* fsin = (const float*)d_in[2];
    const float* wq   = (const float*)d_in[3];
    const float* bq   = (const float*)d_in[4];
    const float* wk   = (const float*)d_in[5];
    const float* bk   = (const float*)d_in[6];
    const float* wv   = (const float*)d_in[7];
    const float* bv   = (const float*)d_in[8];
    const float* wo   = (const float*)d_in[9];
    const float* bo   = (const float*)d_in[10];
    float* out = (float*)d_out;

    char* ws = (char*)d_ws;
    size_t off = 0;
    auto alloc = [&](size_t bytes) { char* p = ws + off; off += (bytes + 255) & ~(size_t)255; return p; };

    unsigned short* Xb   = (unsigned short*)alloc((size_t)ROWS * DIMN * 2);
    unsigned short* Wcat = (unsigned short*)alloc((size_t)NQKV * DIMN * 2);
    unsigned short* Wo2  = (unsigned short*)alloc((size_t)DIMN * DIMN * 2);
    unsigned short* QKV  = (unsigned short*)alloc((size_t)ROWS * NQKV * 2);
    float*          part = (float*)alloc((size_t)32 * 8 * HD * HD * 4);
    unsigned short* M2t  = (unsigned short*)alloc((size_t)32 * HD * HD * 2);
    unsigned short* W2   = (unsigned short*)alloc((size_t)BSZ * DIMN * DIMN * 2);

    // all converts in one launch
    cvt_all<<<24576, 256, 0, stream>>>(x, wq, wk, wv, wo, Xb, Wcat, Wo2);

    // fused QKV projection + bias + RoPE  (M=4096, N=6144, K=2048): 384 blocks
    gemm256<0><<<384, 512, 0, stream>>>(
        Xb, DIMN, Wcat, DIMN, bq, bk, bv, fcos, fsin, QKV, NQKV, DIMN);

    // reassociated attention (no softmax): M2t = (K^T V)^T/sqrt(d) per (b,h)
    ktv_kernel<<<dim3(8, 32), 256, 0, stream>>>(QKV, part);
    ktv_reduce<<<(32 * 16384) / 256, 256, 0, stream>>>(part, M2t);

    // fold attention + output projection: W2_b = concat_h(Wo_h @ M2_{b,h})
    w2_gemm<<<dim3(16, 32), 256, 0, stream>>>(Wo2, M2t, W2);

    // out = Q @ W2_b^T + bo  (M=4096, N=2048 per batch, K=2048): 128 blocks
    gemm256<1><<<128, 512, 0, stream>>>(
        QKV, NQKV, W2, DIMN, bo, nullptr, nullptr, nullptr, nullptr, out, DIMN, DIMN);
}